// Round 11
// baseline (152.708 us; speedup 1.0000x reference)
//
#include <hip/hip_runtime.h>
#include <cstdint>

// Problem: B=8, C=512, H=W=32 -> N=1024, heads=8, hd=64, groups=8.
// Contract (proven R4): inputs fp32, output fp32 (harness compares bf16-rounded).
// Round 11: attn v6 — 64 Q-rows per wave (rs=4), 128-thread blocks (2 waves),
// K/V frag reads amortized over 2x rows (per-work LDS cost 1.5x down). Grid 512
// (64 bh x 8 nblk) = 2 blocks/CU. All other kernels byte-identical to R10.

typedef __bf16 bf16_t;
typedef bf16_t bf16x8 __attribute__((ext_vector_type(8)));
typedef float f32x4 __attribute__((ext_vector_type(4)));

__device__ __forceinline__ uint16_t f2bf(float f) {
  uint32_t x = __builtin_bit_cast(uint32_t, f);
  x += 0x7FFFu + ((x >> 16) & 1u);   // RNE
  return (uint16_t)(x >> 16);
}
__device__ __forceinline__ bf16x8 frag_ld(const uint16_t* p) {
  return __builtin_bit_cast(bf16x8, *(const uint4*)p);
}
__device__ __forceinline__ void gl_lds16(const uint16_t* g, uint16_t* l) {
  __builtin_amdgcn_global_load_lds(
      (const __attribute__((address_space(1))) uint32_t*)g,
      (__attribute__((address_space(3))) uint32_t*)l, 16, 0, 0);
}
#define MFMA16(a, b, c) __builtin_amdgcn_mfma_f32_16x16x32_bf16((a), (b), (c), 0, 0, 0)

// ---------------- prep: weight fp32->bf16 (bx<512) + partial GN stats (bx>=512) -----
__global__ __launch_bounds__(256) void prep_k(const float* __restrict__ wq,
                                              const float* __restrict__ wp,
                                              uint16_t* __restrict__ wqb,
                                              uint16_t* __restrict__ wpb,
                                              const float* __restrict__ x,
                                              float* __restrict__ stats) {
  __shared__ alignas(16) float r1[256];
  __shared__ alignas(16) float r2[256];
  int bx = blockIdx.x, t = threadIdx.x;
  if (bx < 512) {
    int idx = (bx * 256 + t) * 8;
    const float* s;
    uint16_t* d;
    if (idx < 786432) { s = wq + idx; d = wqb + idx; }
    else              { s = wp + (idx - 786432); d = wpb + (idx - 786432); }
    float4 a = *(const float4*)s;
    float4 b = *(const float4*)(s + 4);
    union { uint16_t u[8]; uint4 v; } o;
    o.u[0] = f2bf(a.x); o.u[1] = f2bf(a.y); o.u[2] = f2bf(a.z); o.u[3] = f2bf(a.w);
    o.u[4] = f2bf(b.x); o.u[5] = f2bf(b.y); o.u[6] = f2bf(b.z); o.u[7] = f2bf(b.w);
    *(uint4*)d = o.v;
    return;
  }
  int pg = bx - 512;                         // 0..255: (b*8+g)*4 + part
  const float4* p4 = (const float4*)(x + (size_t)(pg >> 2) * 65536 + (pg & 3) * 16384);
  float s1 = 0.f, s2 = 0.f;
  for (int i = t; i < 4096; i += 256) {
    float4 u = p4[i];
    s1 += u.x + u.y + u.z + u.w;
    s2 += u.x * u.x + u.y * u.y + u.z * u.z + u.w * u.w;
  }
  r1[t] = s1; r2[t] = s2; __syncthreads();
  for (int o = 128; o > 0; o >>= 1) {
    if (t < o) { r1[t] += r1[t + o]; r2[t] += r2[t + o]; }
    __syncthreads();
  }
  if (t == 0) { stats[pg * 2] = r1[0]; stats[pg * 2 + 1] = r2[0]; }
}

// ---------------- normalize + transpose: x fp32 (B,C,N) -> xn bf16 (B,N,C) ----------
__global__ __launch_bounds__(256) void gn_apply_k(const float* __restrict__ x,
                                                  const float* __restrict__ gamma,
                                                  const float* __restrict__ beta,
                                                  const float* __restrict__ stats,
                                                  uint16_t* __restrict__ xn) {
  int nt = blockIdx.x, g = blockIdx.y, b = blockIdx.z;
  int n0 = nt * 64;
  int bg = b * 8 + g;
  float s1 = 0.f, s2 = 0.f;
#pragma unroll
  for (int p = 0; p < 4; p++) { s1 += stats[(bg * 4 + p) * 2]; s2 += stats[(bg * 4 + p) * 2 + 1]; }
  float mu   = s1 * (1.0f / 65536.0f);
  float var  = s2 * (1.0f / 65536.0f) - mu * mu;
  float rstd = rsqrtf(var + 1e-5f);
  __shared__ alignas(16) uint16_t tile[64][72];
  int t = threadIdx.x;
  {
    int c_loc = t >> 2;
    int nch = (t & 3) * 16;
    int c = g * 64 + c_loc;
    float gm = gamma[c], bt = beta[c];
    const float* src = x + (size_t)b * 524288 + (size_t)c * 1024 + n0 + nch;
#pragma unroll
    for (int hh = 0; hh < 2; hh++) {
      float4 u0 = *(const float4*)(src + hh * 8);
      float4 u1 = *(const float4*)(src + hh * 8 + 4);
      union { uint16_t u16[8]; uint4 v; } o;
      o.u16[0] = f2bf((u0.x - mu) * rstd * gm + bt);
      o.u16[1] = f2bf((u0.y - mu) * rstd * gm + bt);
      o.u16[2] = f2bf((u0.z - mu) * rstd * gm + bt);
      o.u16[3] = f2bf((u0.w - mu) * rstd * gm + bt);
      o.u16[4] = f2bf((u1.x - mu) * rstd * gm + bt);
      o.u16[5] = f2bf((u1.y - mu) * rstd * gm + bt);
      o.u16[6] = f2bf((u1.z - mu) * rstd * gm + bt);
      o.u16[7] = f2bf((u1.w - mu) * rstd * gm + bt);
      *(uint4*)&tile[c_loc][nch + hh * 8] = o.v;
    }
  }
  __syncthreads();
  {
    int n_loc = t >> 2;
    int c0 = (t & 3) * 16;
    union { uint16_t u16[16]; uint4 v[2]; } o;
#pragma unroll
    for (int j = 0; j < 16; j++) o.u16[j] = tile[c0 + j][n_loc];
    uint16_t* dst = xn + (size_t)b * 524288 + (size_t)(n0 + n_loc) * 512 + g * 64 + c0;
    *(uint4*)dst = o.v[0];
    *(uint4*)(dst + 8) = o.v[1];
  }
}

// ---------------- shared 128x128 GEMM body, BK=64, XOR-swizzled LDS -----------------
template <int MODE>
__device__ __forceinline__ void gemm_body(uint16_t* Sh,
                                          const uint16_t* Arow, const uint16_t* Brow,
                                          uint16_t* O0, uint16_t* O1,
                                          int b, int n0, int o0) {
  uint16_t* As = Sh;            // 128*64
  uint16_t* Bs = Sh + 8192;     // 128*64
  int t = threadIdx.x;
  int lane = t & 63, w = t >> 6;
  int qd = lane >> 4, l15 = lane & 15;
  int wm = w & 1, wn = w >> 1;

  const uint16_t* gA[4];
  const uint16_t* gB[4];
  uint16_t* lA[4];
  uint16_t* lB[4];
#pragma unroll
  for (int i = 0; i < 4; i++) {
    int p = i * 256 + t;
    int row = p >> 3, slot = p & 7, gc = slot ^ (row & 7);
    gA[i] = Arow + (size_t)row * 512 + gc * 8;
    gB[i] = Brow + (size_t)row * 512 + gc * 8;
    lA[i] = As + (size_t)(p - lane) * 8;
    lB[i] = Bs + (size_t)(p - lane) * 8;
  }

  f32x4 acc[4][4] = {};

  for (int k0 = 0; k0 < 512; k0 += 64) {
    __syncthreads();
#pragma unroll
    for (int i = 0; i < 4; i++) { gl_lds16(gA[i] + k0, lA[i]); gl_lds16(gB[i] + k0, lB[i]); }
    __syncthreads();

#pragma unroll
    for (int h = 0; h < 2; h++) {
      int slot = (h * 4 + qd) ^ (l15 & 7);
      bf16x8 af[4], bfr[4];
#pragma unroll
      for (int mt = 0; mt < 4; mt++)
        af[mt] = frag_ld(As + (wm * 64 + mt * 16 + l15) * 64 + slot * 8);
#pragma unroll
      for (int nt2 = 0; nt2 < 4; nt2++)
        bfr[nt2] = frag_ld(Bs + (wn * 64 + nt2 * 16 + l15) * 64 + slot * 8);
#pragma unroll
      for (int mt = 0; mt < 4; mt++)
#pragma unroll
        for (int nt2 = 0; nt2 < 4; nt2++)
          acc[mt][nt2] = MFMA16(af[mt], bfr[nt2], acc[mt][nt2]);
    }
  }

  // LDS-transpose epilogue -> coalesced 16B stores
  __syncthreads();
  uint16_t* buf = Sh + w * 1152;        // 16 x 72 per wave
  float sc = 1.0f;
  uint16_t* gbase;
  size_t rstride;
  int coff;
  if constexpr (MODE == 0) {
    int oc = o0 + wn * 64;              // 64-col band = one head
    int hh;
    uint16_t* db;
    if (oc < 512) { db = O0; hh = oc >> 6; sc = 0.125f; }   // Q pre-scale 1/8
    else          { db = O1; hh = (oc - 512) >> 6; }
    gbase = db + (size_t)(b * 8 + hh) * 65536 + (size_t)(n0 + wm * 64) * 64;
    rstride = 64;  coff = 0;
  } else {
    gbase = O0 + (size_t)b * 524288 + (size_t)(o0 + wm * 64) * 1024;
    rstride = 1024; coff = n0 + wn * 64;
  }
  int jrow = lane >> 3, joff = (lane & 7) * 8;
#pragma unroll
  for (int mt = 0; mt < 4; mt++) {
#pragma unroll
    for (int nt2 = 0; nt2 < 4; nt2++)
#pragma unroll
      for (int r = 0; r < 4; r++)
        buf[(qd * 4 + r) * 72 + nt2 * 16 + l15] = f2bf(acc[mt][nt2][r] * sc);
#pragma unroll
    for (int half = 0; half < 2; half++) {
      int row = jrow + half * 8;
      uint4 v = *(const uint4*)(buf + row * 72 + joff);
      *(uint4*)(gbase + (size_t)(mt * 16 + row) * rstride + coff + joff) = v;
    }
  }
}

// fused QKV, XCD-local 1D grid: id&7 = n-band
__global__ __launch_bounds__(256) void gemm01_k(const uint16_t* __restrict__ xn,
                                                const uint16_t* __restrict__ wqb,
                                                uint16_t* __restrict__ qtw,
                                                uint16_t* __restrict__ ktw,
                                                uint16_t* __restrict__ vtw) {
  __shared__ alignas(16) uint16_t Sh[16384];
  int id = blockIdx.x;                  // 768
  int lo = id & 7, hi = id >> 3;        // hi 0..95
  int o12 = hi % 12, b = hi / 12;       // b 0..7
  int n0 = lo * 128;
  if (o12 < 8) {
    int o0 = o12 * 128;
    gemm_body<0>(Sh, xn + (size_t)b * 524288 + (size_t)n0 * 512,
                 wqb + (size_t)o0 * 512, qtw, ktw, b, n0, o0);
  } else {
    int o0 = (o12 - 8) * 128;
    gemm_body<1>(Sh, wqb + (size_t)(1024 + o0) * 512,
                 xn + (size_t)b * 524288 + (size_t)n0 * 512, vtw, nullptr, b, n0, o0);
  }
}

// proj GEMM: XCD swizzle + async double-buffered BK=64 -> fp32 out (+x, +bias)
__global__ __launch_bounds__(256) void gemm2_k(const uint16_t* __restrict__ wpb,
                                               const uint16_t* __restrict__ otw,
                                               const float* __restrict__ xres,
                                               const float* __restrict__ biasf,
                                               float* __restrict__ out) {
  __shared__ alignas(16) uint16_t As[2][8192];
  __shared__ alignas(16) uint16_t Bs[2][8192];
  int id = blockIdx.x;                  // 256
  int lo = id & 7, hi = id >> 3;        // hi 0..31
  int o0 = (hi & 3) * 128, b = hi >> 2, n0 = lo * 128;
  const uint16_t* Arow = wpb + (size_t)o0 * 512;
  const uint16_t* Brow = otw + (size_t)b * 524288 + (size_t)n0 * 512;

  int t = threadIdx.x, lane = t & 63, w = t >> 6;
  int qd = lane >> 4, l15 = lane & 15;
  int wm = w & 1, wn = w >> 1;

  const uint16_t* gA[4];
  const uint16_t* gB[4];
  int lofs[4];
#pragma unroll
  for (int i = 0; i < 4; i++) {
    int p = i * 256 + t;
    int row = p >> 3, slot = p & 7, gc = slot ^ (row & 7);
    gA[i] = Arow + (size_t)row * 512 + gc * 8;
    gB[i] = Brow + (size_t)row * 512 + gc * 8;
    lofs[i] = (p - lane) * 8;
  }

  f32x4 acc[4][4] = {};
#pragma unroll
  for (int i = 0; i < 4; i++) { gl_lds16(gA[i], &As[0][lofs[i]]); gl_lds16(gB[i], &Bs[0][lofs[i]]); }
  __syncthreads();

  for (int kt = 0; kt < 8; kt++) {
    int cur = kt & 1, nxt = cur ^ 1;
    if (kt < 7) {
      int k0 = (kt + 1) * 64;
#pragma unroll
      for (int i = 0; i < 4; i++) { gl_lds16(gA[i] + k0, &As[nxt][lofs[i]]); gl_lds16(gB[i] + k0, &Bs[nxt][lofs[i]]); }
    }
#pragma unroll
    for (int h = 0; h < 2; h++) {
      int slot = (h * 4 + qd) ^ (l15 & 7);
      bf16x8 af[4], bfr[4];
#pragma unroll
      for (int mt = 0; mt < 4; mt++)
        af[mt] = frag_ld(&As[cur][(wm * 64 + mt * 16 + l15) * 64 + slot * 8]);
#pragma unroll
      for (int nt2 = 0; nt2 < 4; nt2++)
        bfr[nt2] = frag_ld(&Bs[cur][(wn * 64 + nt2 * 16 + l15) * 64 + slot * 8]);
#pragma unroll
      for (int mt = 0; mt < 4; mt++)
#pragma unroll
        for (int nt2 = 0; nt2 < 4; nt2++)
          acc[mt][nt2] = MFMA16(af[mt], bfr[nt2], acc[mt][nt2]);
    }
    __syncthreads();
  }

#pragma unroll
  for (int mt = 0; mt < 4; mt++) {
    int row = wm * 64 + mt * 16 + qd * 4;
#pragma unroll
    for (int nt2 = 0; nt2 < 4; nt2++) {
      int col = wn * 64 + nt2 * 16 + l15;
#pragma unroll
      for (int r = 0; r < 4; r++) {
        int orow = o0 + row + r, n = n0 + col;
        size_t idx = (size_t)b * 524288 + (size_t)orow * 1024 + n;
        out[idx] = xres[idx] + biasf[orow] + acc[mt][nt2][r];
      }
    }
  }
}

// ---------------- flash attention v6: 64 Q-rows/wave, 2-wave blocks -----------------
// 128 rows/block (2 waves x rs=4 x 16), BN=64, dbuf K/V via gl_lds16 (XOR-swizzled),
// 1 barrier/iter. K/V frag reads shared across 4 rowsets. S^T/O^T formulation (R7).
__global__ __launch_bounds__(128) void attn_k(const uint16_t* __restrict__ qt,
                                              const uint16_t* __restrict__ ktp,
                                              const uint16_t* __restrict__ vtp,
                                              uint16_t* __restrict__ ot) {
  int bh = blockIdx.x;                            // bh mod 8 -> XCD-local heads
  int b = bh >> 3, h = bh & 7;
  int n0 = blockIdx.y * 128;
  const uint16_t* qbase = qt + (size_t)bh * 65536;              // (n,d)
  const uint16_t* kbase = ktp + (size_t)bh * 65536;             // (m,d)
  const uint16_t* vbase = vtp + (size_t)b * 524288 + (size_t)h * 65536;  // (d,m)

  __shared__ alignas(16) uint16_t Ks[2][4096];    // [key][d] swizzled
  __shared__ alignas(16) uint16_t Vs[2][4096];    // [d][m]   swizzled
  __shared__ alignas(16) uint16_t Ps[128 * 72];   // [n][m] P^T rows (wave-private)

  int t = threadIdx.x, lane = t & 63, w = t >> 6; // w 0..1
  int qd = lane >> 4, l15 = lane & 15;

  bf16x8 qf[4][2];                                // 4 rowsets x (k 0..31, 32..63)
#pragma unroll
  for (int rs = 0; rs < 4; rs++) {
    const uint16_t* qp = qbase + (size_t)(n0 + w * 64 + rs * 16 + l15) * 64 + qd * 8;
    qf[rs][0] = frag_ld(qp);
    qf[rs][1] = frag_ld(qp + 32);
  }

  // staging: 512 chunks per tile / 128 threads = 4 each
  const uint16_t* gK[4];
  const uint16_t* gV[4];
  int lofs[4];
#pragma unroll
  for (int i = 0; i < 4; i++) {
    int p = i * 128 + t;
    int row = p >> 3, slot = p & 7, gc = slot ^ (row & 7);
    gK[i] = kbase + (size_t)row * 64 + gc * 8;     // + m0*64 per iter
    gV[i] = vbase + (size_t)row * 1024 + gc * 8;   // + m0 per iter
    lofs[i] = (p - lane) * 8;
  }

  f32x4 oaccT[4][4] = {};                         // [rs][dt]
  float lsum[4] = {0.f, 0.f, 0.f, 0.f};

#pragma unroll
  for (int i = 0; i < 4; i++) { gl_lds16(gK[i], &Ks[0][lofs[i]]); gl_lds16(gV[i], &Vs[0][lofs[i]]); }
  __syncthreads();

  for (int it = 0; it < 16; it++) {
    int cur = it & 1, nxt = cur ^ 1;
    const uint16_t* Kc = Ks[cur];
    const uint16_t* Vc = Vs[cur];

    // S^T = K Q^T : kf shared across 4 rowsets
    f32x4 sacc[4][4];                             // [rs][mt]
#pragma unroll
    for (int mt = 0; mt < 4; mt++) {
      int row = mt * 16 + l15;
      int s0 = qd ^ (l15 & 7);
      bf16x8 kf0 = frag_ld(Kc + (size_t)row * 64 + s0 * 8);
      bf16x8 kf1 = frag_ld(Kc + (size_t)row * 64 + (s0 ^ 4) * 8);
#pragma unroll
      for (int rs = 0; rs < 4; rs++) {
        f32x4 z = {};
        z = MFMA16(kf0, qf[rs][0], z);
        sacc[rs][mt] = MFMA16(kf1, qf[rs][1], z);
      }
    }

    if (it < 15) {                                // async prefetch tile it+1
      int m0 = (it + 1) * 64;
#pragma unroll
      for (int i = 0; i < 4; i++) {
        gl_lds16(gK[i] + (size_t)m0 * 64, &Ks[nxt][lofs[i]]);
        gl_lds16(gV[i] + m0, &Vs[nxt][lofs[i]]);
      }
    }

    // p = exp(s); pack 4 consecutive keys -> b64 into P^T (wave-private rows)
#pragma unroll
    for (int rs = 0; rs < 4; rs++)
#pragma unroll
      for (int mt = 0; mt < 4; mt++) {
        union { uint16_t u[4]; uint2 v; } pk;
        float psum = 0.f;
#pragma unroll
        for (int r = 0; r < 4; r++) {
          float p = __expf(sacc[rs][mt][r]);
          psum += p;
          pk.u[r] = (uint16_t)(__builtin_bit_cast(uint32_t, p) >> 16);
        }
        lsum[rs] += psum;
        *(uint2*)(Ps + (size_t)(w * 64 + rs * 16 + l15) * 72 + mt * 16 + qd * 4) = pk.v;
      }

    // O^T += V^T P^T ; vf shared across 4 rowsets (in-order wave-private Ps)
    bf16x8 pf[4][2];
#pragma unroll
    for (int rs = 0; rs < 4; rs++)
#pragma unroll
      for (int ks = 0; ks < 2; ks++)
        pf[rs][ks] = frag_ld(Ps + (size_t)(w * 64 + rs * 16 + l15) * 72 + ks * 32 + qd * 8);
#pragma unroll
    for (int dt = 0; dt < 4; dt++)
#pragma unroll
      for (int ks = 0; ks < 2; ks++) {
        int row = dt * 16 + l15;
        int slot = (ks * 4 + qd) ^ (l15 & 7);
        bf16x8 vf = frag_ld(Vc + (size_t)row * 64 + slot * 8);
#pragma unroll
        for (int rs = 0; rs < 4; rs++)
          oaccT[rs][dt] = MFMA16(vf, pf[rs][ks], oaccT[rs][dt]);
      }

    __syncthreads();   // all waves done with cur; drains prefetch into nxt
  }

  // epilogue: reduce lsum over qd groups, normalize, pack 4 d-values -> 8B stores
#pragma unroll
  for (int rs = 0; rs < 4; rs++) {
    float s = lsum[rs];
    s += __shfl_xor(s, 16);
    s += __shfl_xor(s, 32);
    float rinv = 1.0f / s;
    int n = n0 + w * 64 + rs * 16 + l15;
    uint16_t* orow = ot + (size_t)b * 524288 + (size_t)n * 512 + h * 64;
#pragma unroll
    for (int dt = 0; dt < 4; dt++) {
      union { uint16_t u[4]; uint2 v; } pk;
#pragma unroll
      for (int r = 0; r < 4; r++) pk.u[r] = f2bf(oaccT[rs][dt][r] * rinv);
      *(uint2*)(orow + dt * 16 + qd * 4) = pk.v;
    }
  }
}

extern "C" void kernel_launch(void* const* d_in, const int* in_sizes, int n_in,
                              void* d_out, int out_size, void* d_ws, size_t ws_size,
                              hipStream_t stream) {
  (void)in_sizes; (void)n_in; (void)out_size; (void)ws_size;
  const float* xf   = (const float*)d_in[0];
  const float* gamf = (const float*)d_in[1];
  const float* betf = (const float*)d_in[2];
  const float* wqf  = (const float*)d_in[3];
  const float* wpf  = (const float*)d_in[4];
  const float* bprf = (const float*)d_in[5];
  float* out = (float*)d_out;

  uint16_t* base = (uint16_t*)d_ws;
  float* stats   = (float*)base;           // 512 floats (partial s1,s2 x 256)
  uint16_t* wqb  = base + 1024;
  uint16_t* wpb  = wqb + 786432;
  uint16_t* xn   = wpb + 262144;           // (B,N,C); reused as otw after gemm01
  uint16_t* qtw  = xn  + 4194304;          // (B,H,N,hd), Q pre-scaled by 1/8
  uint16_t* ktw  = qtw + 4194304;          // (B,H,N,hd)
  uint16_t* vtw  = ktw + 4194304;          // (B, h*64+d, N)
  uint16_t* otw  = xn;

  prep_k<<<768, 256, 0, stream>>>(wqf, wpf, wqb, wpb, xf, stats);
  gn_apply_k<<<dim3(16, 8, 8), 256, 0, stream>>>(xf, gamf, betf, stats, xn);
  gemm01_k<<<768, 256, 0, stream>>>(xn, wqb, qtw, ktw, vtw);
  attn_k<<<dim3(64, 8), 128, 0, stream>>>(qtw, ktw, vtw, otw);
  gemm2_k<<<256, 256, 0, stream>>>(wpb, otw, xf, bprf, out);
}

// Round 12
// 149.549 us; speedup vs baseline: 1.0211x; 1.0211x over previous
//
#include <hip/hip_runtime.h>
#include <cstdint>

// Problem: B=8, C=512, H=W=32 -> N=1024, heads=8, hd=64, groups=8.
// Contract (proven R4): inputs fp32, output fp32 (harness compares bf16-rounded).
// Round 12: revert attn to R10 v5 (256-thr, rs=2 — R11's 64-row/wave variant
// halved occupancy, +5 µs). Single tweak: K/V prefetch issued at TOP of iter
// (safe: nxt buffer's readers finished at the previous barrier) for one extra
// MFMA-block of async-load cover. All other kernels byte-identical to R10.

typedef __bf16 bf16_t;
typedef bf16_t bf16x8 __attribute__((ext_vector_type(8)));
typedef float f32x4 __attribute__((ext_vector_type(4)));

__device__ __forceinline__ uint16_t f2bf(float f) {
  uint32_t x = __builtin_bit_cast(uint32_t, f);
  x += 0x7FFFu + ((x >> 16) & 1u);   // RNE
  return (uint16_t)(x >> 16);
}
__device__ __forceinline__ bf16x8 frag_ld(const uint16_t* p) {
  return __builtin_bit_cast(bf16x8, *(const uint4*)p);
}
__device__ __forceinline__ void gl_lds16(const uint16_t* g, uint16_t* l) {
  __builtin_amdgcn_global_load_lds(
      (const __attribute__((address_space(1))) uint32_t*)g,
      (__attribute__((address_space(3))) uint32_t*)l, 16, 0, 0);
}
#define MFMA16(a, b, c) __builtin_amdgcn_mfma_f32_16x16x32_bf16((a), (b), (c), 0, 0, 0)

// ---------------- prep: weight fp32->bf16 (bx<512) + partial GN stats (bx>=512) -----
__global__ __launch_bounds__(256) void prep_k(const float* __restrict__ wq,
                                              const float* __restrict__ wp,
                                              uint16_t* __restrict__ wqb,
                                              uint16_t* __restrict__ wpb,
                                              const float* __restrict__ x,
                                              float* __restrict__ stats) {
  __shared__ alignas(16) float r1[256];
  __shared__ alignas(16) float r2[256];
  int bx = blockIdx.x, t = threadIdx.x;
  if (bx < 512) {
    int idx = (bx * 256 + t) * 8;
    const float* s;
    uint16_t* d;
    if (idx < 786432) { s = wq + idx; d = wqb + idx; }
    else              { s = wp + (idx - 786432); d = wpb + (idx - 786432); }
    float4 a = *(const float4*)s;
    float4 b = *(const float4*)(s + 4);
    union { uint16_t u[8]; uint4 v; } o;
    o.u[0] = f2bf(a.x); o.u[1] = f2bf(a.y); o.u[2] = f2bf(a.z); o.u[3] = f2bf(a.w);
    o.u[4] = f2bf(b.x); o.u[5] = f2bf(b.y); o.u[6] = f2bf(b.z); o.u[7] = f2bf(b.w);
    *(uint4*)d = o.v;
    return;
  }
  int pg = bx - 512;                         // 0..255: (b*8+g)*4 + part
  const float4* p4 = (const float4*)(x + (size_t)(pg >> 2) * 65536 + (pg & 3) * 16384);
  float s1 = 0.f, s2 = 0.f;
  for (int i = t; i < 4096; i += 256) {
    float4 u = p4[i];
    s1 += u.x + u.y + u.z + u.w;
    s2 += u.x * u.x + u.y * u.y + u.z * u.z + u.w * u.w;
  }
  r1[t] = s1; r2[t] = s2; __syncthreads();
  for (int o = 128; o > 0; o >>= 1) {
    if (t < o) { r1[t] += r1[t + o]; r2[t] += r2[t + o]; }
    __syncthreads();
  }
  if (t == 0) { stats[pg * 2] = r1[0]; stats[pg * 2 + 1] = r2[0]; }
}

// ---------------- normalize + transpose: x fp32 (B,C,N) -> xn bf16 (B,N,C) ----------
__global__ __launch_bounds__(256) void gn_apply_k(const float* __restrict__ x,
                                                  const float* __restrict__ gamma,
                                                  const float* __restrict__ beta,
                                                  const float* __restrict__ stats,
                                                  uint16_t* __restrict__ xn) {
  int nt = blockIdx.x, g = blockIdx.y, b = blockIdx.z;
  int n0 = nt * 64;
  int bg = b * 8 + g;
  float s1 = 0.f, s2 = 0.f;
#pragma unroll
  for (int p = 0; p < 4; p++) { s1 += stats[(bg * 4 + p) * 2]; s2 += stats[(bg * 4 + p) * 2 + 1]; }
  float mu   = s1 * (1.0f / 65536.0f);
  float var  = s2 * (1.0f / 65536.0f) - mu * mu;
  float rstd = rsqrtf(var + 1e-5f);
  __shared__ alignas(16) uint16_t tile[64][72];
  int t = threadIdx.x;
  {
    int c_loc = t >> 2;
    int nch = (t & 3) * 16;
    int c = g * 64 + c_loc;
    float gm = gamma[c], bt = beta[c];
    const float* src = x + (size_t)b * 524288 + (size_t)c * 1024 + n0 + nch;
#pragma unroll
    for (int hh = 0; hh < 2; hh++) {
      float4 u0 = *(const float4*)(src + hh * 8);
      float4 u1 = *(const float4*)(src + hh * 8 + 4);
      union { uint16_t u16[8]; uint4 v; } o;
      o.u16[0] = f2bf((u0.x - mu) * rstd * gm + bt);
      o.u16[1] = f2bf((u0.y - mu) * rstd * gm + bt);
      o.u16[2] = f2bf((u0.z - mu) * rstd * gm + bt);
      o.u16[3] = f2bf((u0.w - mu) * rstd * gm + bt);
      o.u16[4] = f2bf((u1.x - mu) * rstd * gm + bt);
      o.u16[5] = f2bf((u1.y - mu) * rstd * gm + bt);
      o.u16[6] = f2bf((u1.z - mu) * rstd * gm + bt);
      o.u16[7] = f2bf((u1.w - mu) * rstd * gm + bt);
      *(uint4*)&tile[c_loc][nch + hh * 8] = o.v;
    }
  }
  __syncthreads();
  {
    int n_loc = t >> 2;
    int c0 = (t & 3) * 16;
    union { uint16_t u16[16]; uint4 v[2]; } o;
#pragma unroll
    for (int j = 0; j < 16; j++) o.u16[j] = tile[c0 + j][n_loc];
    uint16_t* dst = xn + (size_t)b * 524288 + (size_t)(n0 + n_loc) * 512 + g * 64 + c0;
    *(uint4*)dst = o.v[0];
    *(uint4*)(dst + 8) = o.v[1];
  }
}

// ---------------- shared 128x128 GEMM body, BK=64, XOR-swizzled LDS -----------------
template <int MODE>
__device__ __forceinline__ void gemm_body(uint16_t* Sh,
                                          const uint16_t* Arow, const uint16_t* Brow,
                                          uint16_t* O0, uint16_t* O1,
                                          int b, int n0, int o0) {
  uint16_t* As = Sh;            // 128*64
  uint16_t* Bs = Sh + 8192;     // 128*64
  int t = threadIdx.x;
  int lane = t & 63, w = t >> 6;
  int qd = lane >> 4, l15 = lane & 15;
  int wm = w & 1, wn = w >> 1;

  const uint16_t* gA[4];
  const uint16_t* gB[4];
  uint16_t* lA[4];
  uint16_t* lB[4];
#pragma unroll
  for (int i = 0; i < 4; i++) {
    int p = i * 256 + t;
    int row = p >> 3, slot = p & 7, gc = slot ^ (row & 7);
    gA[i] = Arow + (size_t)row * 512 + gc * 8;
    gB[i] = Brow + (size_t)row * 512 + gc * 8;
    lA[i] = As + (size_t)(p - lane) * 8;
    lB[i] = Bs + (size_t)(p - lane) * 8;
  }

  f32x4 acc[4][4] = {};

  for (int k0 = 0; k0 < 512; k0 += 64) {
    __syncthreads();
#pragma unroll
    for (int i = 0; i < 4; i++) { gl_lds16(gA[i] + k0, lA[i]); gl_lds16(gB[i] + k0, lB[i]); }
    __syncthreads();

#pragma unroll
    for (int h = 0; h < 2; h++) {
      int slot = (h * 4 + qd) ^ (l15 & 7);
      bf16x8 af[4], bfr[4];
#pragma unroll
      for (int mt = 0; mt < 4; mt++)
        af[mt] = frag_ld(As + (wm * 64 + mt * 16 + l15) * 64 + slot * 8);
#pragma unroll
      for (int nt2 = 0; nt2 < 4; nt2++)
        bfr[nt2] = frag_ld(Bs + (wn * 64 + nt2 * 16 + l15) * 64 + slot * 8);
#pragma unroll
      for (int mt = 0; mt < 4; mt++)
#pragma unroll
        for (int nt2 = 0; nt2 < 4; nt2++)
          acc[mt][nt2] = MFMA16(af[mt], bfr[nt2], acc[mt][nt2]);
    }
  }

  // LDS-transpose epilogue -> coalesced 16B stores
  __syncthreads();
  uint16_t* buf = Sh + w * 1152;        // 16 x 72 per wave
  float sc = 1.0f;
  uint16_t* gbase;
  size_t rstride;
  int coff;
  if constexpr (MODE == 0) {
    int oc = o0 + wn * 64;              // 64-col band = one head
    int hh;
    uint16_t* db;
    if (oc < 512) { db = O0; hh = oc >> 6; sc = 0.125f; }   // Q pre-scale 1/8
    else          { db = O1; hh = (oc - 512) >> 6; }
    gbase = db + (size_t)(b * 8 + hh) * 65536 + (size_t)(n0 + wm * 64) * 64;
    rstride = 64;  coff = 0;
  } else {
    gbase = O0 + (size_t)b * 524288 + (size_t)(o0 + wm * 64) * 1024;
    rstride = 1024; coff = n0 + wn * 64;
  }
  int jrow = lane >> 3, joff = (lane & 7) * 8;
#pragma unroll
  for (int mt = 0; mt < 4; mt++) {
#pragma unroll
    for (int nt2 = 0; nt2 < 4; nt2++)
#pragma unroll
      for (int r = 0; r < 4; r++)
        buf[(qd * 4 + r) * 72 + nt2 * 16 + l15] = f2bf(acc[mt][nt2][r] * sc);
#pragma unroll
    for (int half = 0; half < 2; half++) {
      int row = jrow + half * 8;
      uint4 v = *(const uint4*)(buf + row * 72 + joff);
      *(uint4*)(gbase + (size_t)(mt * 16 + row) * rstride + coff + joff) = v;
    }
  }
}

// fused QKV, XCD-local 1D grid: id&7 = n-band
__global__ __launch_bounds__(256) void gemm01_k(const uint16_t* __restrict__ xn,
                                                const uint16_t* __restrict__ wqb,
                                                uint16_t* __restrict__ qtw,
                                                uint16_t* __restrict__ ktw,
                                                uint16_t* __restrict__ vtw) {
  __shared__ alignas(16) uint16_t Sh[16384];
  int id = blockIdx.x;                  // 768
  int lo = id & 7, hi = id >> 3;        // hi 0..95
  int o12 = hi % 12, b = hi / 12;       // b 0..7
  int n0 = lo * 128;
  if (o12 < 8) {
    int o0 = o12 * 128;
    gemm_body<0>(Sh, xn + (size_t)b * 524288 + (size_t)n0 * 512,
                 wqb + (size_t)o0 * 512, qtw, ktw, b, n0, o0);
  } else {
    int o0 = (o12 - 8) * 128;
    gemm_body<1>(Sh, wqb + (size_t)(1024 + o0) * 512,
                 xn + (size_t)b * 524288 + (size_t)n0 * 512, vtw, nullptr, b, n0, o0);
  }
}

// proj GEMM: XCD swizzle + async double-buffered BK=64 -> fp32 out (+x, +bias)
__global__ __launch_bounds__(256) void gemm2_k(const uint16_t* __restrict__ wpb,
                                               const uint16_t* __restrict__ otw,
                                               const float* __restrict__ xres,
                                               const float* __restrict__ biasf,
                                               float* __restrict__ out) {
  __shared__ alignas(16) uint16_t As[2][8192];
  __shared__ alignas(16) uint16_t Bs[2][8192];
  int id = blockIdx.x;                  // 256
  int lo = id & 7, hi = id >> 3;        // hi 0..31
  int o0 = (hi & 3) * 128, b = hi >> 2, n0 = lo * 128;
  const uint16_t* Arow = wpb + (size_t)o0 * 512;
  const uint16_t* Brow = otw + (size_t)b * 524288 + (size_t)n0 * 512;

  int t = threadIdx.x, lane = t & 63, w = t >> 6;
  int qd = lane >> 4, l15 = lane & 15;
  int wm = w & 1, wn = w >> 1;

  const uint16_t* gA[4];
  const uint16_t* gB[4];
  int lofs[4];
#pragma unroll
  for (int i = 0; i < 4; i++) {
    int p = i * 256 + t;
    int row = p >> 3, slot = p & 7, gc = slot ^ (row & 7);
    gA[i] = Arow + (size_t)row * 512 + gc * 8;
    gB[i] = Brow + (size_t)row * 512 + gc * 8;
    lofs[i] = (p - lane) * 8;
  }

  f32x4 acc[4][4] = {};
#pragma unroll
  for (int i = 0; i < 4; i++) { gl_lds16(gA[i], &As[0][lofs[i]]); gl_lds16(gB[i], &Bs[0][lofs[i]]); }
  __syncthreads();

  for (int kt = 0; kt < 8; kt++) {
    int cur = kt & 1, nxt = cur ^ 1;
    if (kt < 7) {
      int k0 = (kt + 1) * 64;
#pragma unroll
      for (int i = 0; i < 4; i++) { gl_lds16(gA[i] + k0, &As[nxt][lofs[i]]); gl_lds16(gB[i] + k0, &Bs[nxt][lofs[i]]); }
    }
#pragma unroll
    for (int h = 0; h < 2; h++) {
      int slot = (h * 4 + qd) ^ (l15 & 7);
      bf16x8 af[4], bfr[4];
#pragma unroll
      for (int mt = 0; mt < 4; mt++)
        af[mt] = frag_ld(&As[cur][(wm * 64 + mt * 16 + l15) * 64 + slot * 8]);
#pragma unroll
      for (int nt2 = 0; nt2 < 4; nt2++)
        bfr[nt2] = frag_ld(&Bs[cur][(wn * 64 + nt2 * 16 + l15) * 64 + slot * 8]);
#pragma unroll
      for (int mt = 0; mt < 4; mt++)
#pragma unroll
        for (int nt2 = 0; nt2 < 4; nt2++)
          acc[mt][nt2] = MFMA16(af[mt], bfr[nt2], acc[mt][nt2]);
    }
    __syncthreads();
  }

#pragma unroll
  for (int mt = 0; mt < 4; mt++) {
    int row = wm * 64 + mt * 16 + qd * 4;
#pragma unroll
    for (int nt2 = 0; nt2 < 4; nt2++) {
      int col = wn * 64 + nt2 * 16 + l15;
#pragma unroll
      for (int r = 0; r < 4; r++) {
        int orow = o0 + row + r, n = n0 + col;
        size_t idx = (size_t)b * 524288 + (size_t)orow * 1024 + n;
        out[idx] = xres[idx] + biasf[orow] + acc[mt][nt2][r];
      }
    }
  }
}

// ---------------- flash attention v5 (R10) + top-of-iter prefetch -------------------
// 128 Q rows/block (4 waves x rs=2 x 16), BN=64, dbuf K/V via gl_lds16 (swizzled),
// 1 barrier/iter. Prefetch for it+1 issued at iter top (nxt readers finished at
// the previous barrier) -> full-iteration async cover.
__global__ __launch_bounds__(256) void attn_k(const uint16_t* __restrict__ qt,
                                              const uint16_t* __restrict__ ktp,
                                              const uint16_t* __restrict__ vtp,
                                              uint16_t* __restrict__ ot) {
  int bh = blockIdx.x;                            // bh mod 8 -> XCD-local heads
  int b = bh >> 3, h = bh & 7;
  int n0 = blockIdx.y * 128;
  const uint16_t* qbase = qt + (size_t)bh * 65536;              // (n,d)
  const uint16_t* kbase = ktp + (size_t)bh * 65536;             // (m,d)
  const uint16_t* vbase = vtp + (size_t)b * 524288 + (size_t)h * 65536;  // (d,m)

  __shared__ alignas(16) uint16_t Ks[2][4096];
  __shared__ alignas(16) uint16_t Vs[2][4096];
  __shared__ alignas(16) uint16_t Ps[128 * 72];

  int t = threadIdx.x, lane = t & 63, w = t >> 6;
  int qd = lane >> 4, l15 = lane & 15;

  bf16x8 qf[2][2];
#pragma unroll
  for (int rs = 0; rs < 2; rs++) {
    const uint16_t* qp = qbase + (size_t)(n0 + w * 32 + rs * 16 + l15) * 64 + qd * 8;
    qf[rs][0] = frag_ld(qp);
    qf[rs][1] = frag_ld(qp + 32);
  }

  // staging: 512 chunks per tile / 256 threads = 2 each, XOR-swizzled slots
  int p1 = t, p2 = t + 256;
  int r1 = p1 >> 3, gc1 = (p1 & 7) ^ (r1 & 7);
  int r2 = p2 >> 3, gc2 = (p2 & 7) ^ (r2 & 7);
  const uint16_t* gK1 = kbase + (size_t)r1 * 64 + gc1 * 8;
  const uint16_t* gK2 = kbase + (size_t)r2 * 64 + gc2 * 8;
  const uint16_t* gV1 = vbase + (size_t)r1 * 1024 + gc1 * 8;
  const uint16_t* gV2 = vbase + (size_t)r2 * 1024 + gc2 * 8;
  int lo1 = (p1 - lane) * 8;
  int lo2 = (p2 - lane) * 8;

  f32x4 oaccT[2][4] = {};
  float lsum[2] = {0.f, 0.f};

  gl_lds16(gK1, &Ks[0][lo1]);
  gl_lds16(gK2, &Ks[0][lo2]);
  gl_lds16(gV1, &Vs[0][lo1]);
  gl_lds16(gV2, &Vs[0][lo2]);
  __syncthreads();

  for (int it = 0; it < 16; it++) {
    int cur = it & 1, nxt = cur ^ 1;
    if (it < 15) {                                // prefetch at iter top (safe:
      int m0 = (it + 1) * 64;                     // nxt readers done at last barrier)
      gl_lds16(gK1 + (size_t)m0 * 64, &Ks[nxt][lo1]);
      gl_lds16(gK2 + (size_t)m0 * 64, &Ks[nxt][lo2]);
      gl_lds16(gV1 + m0, &Vs[nxt][lo1]);
      gl_lds16(gV2 + m0, &Vs[nxt][lo2]);
    }
    const uint16_t* Kc = Ks[cur];
    const uint16_t* Vc = Vs[cur];

    // S^T = K Q^T
    f32x4 sacc[2][4] = {};
#pragma unroll
    for (int mt = 0; mt < 4; mt++) {
      int row = mt * 16 + l15;
      int s0 = qd ^ (l15 & 7);
      bf16x8 kf0 = frag_ld(Kc + (size_t)row * 64 + s0 * 8);
      bf16x8 kf1 = frag_ld(Kc + (size_t)row * 64 + (s0 ^ 4) * 8);
#pragma unroll
      for (int rs = 0; rs < 2; rs++) {
        sacc[rs][mt] = MFMA16(kf0, qf[rs][0], sacc[rs][mt]);
        sacc[rs][mt] = MFMA16(kf1, qf[rs][1], sacc[rs][mt]);
      }
    }

    // p = exp(s); pack 4 consecutive keys -> b64 into P^T (wave-private rows)
#pragma unroll
    for (int rs = 0; rs < 2; rs++)
#pragma unroll
      for (int mt = 0; mt < 4; mt++) {
        union { uint16_t u[4]; uint2 v; } pk;
        float psum = 0.f;
#pragma unroll
        for (int r = 0; r < 4; r++) {
          float p = __expf(sacc[rs][mt][r]);
          psum += p;
          pk.u[r] = (uint16_t)(__builtin_bit_cast(uint32_t, p) >> 16);
        }
        lsum[rs] += psum;
        *(uint2*)(Ps + (size_t)(w * 32 + rs * 16 + l15) * 72 + mt * 16 + qd * 4) = pk.v;
      }

    // O^T += V^T P^T
    bf16x8 pf[2][2];
#pragma unroll
    for (int rs = 0; rs < 2; rs++)
#pragma unroll
      for (int ks = 0; ks < 2; ks++)
        pf[rs][ks] = frag_ld(Ps + (size_t)(w * 32 + rs * 16 + l15) * 72 + ks * 32 + qd * 8);
#pragma unroll
    for (int dt = 0; dt < 4; dt++)
#pragma unroll
      for (int ks = 0; ks < 2; ks++) {
        int row = dt * 16 + l15;
        int slot = (ks * 4 + qd) ^ (l15 & 7);
        bf16x8 vf = frag_ld(Vc + (size_t)row * 64 + slot * 8);
#pragma unroll
        for (int rs = 0; rs < 2; rs++)
          oaccT[rs][dt] = MFMA16(vf, pf[rs][ks], oaccT[rs][dt]);
      }

    __syncthreads();   // all waves done with cur; drains prefetch into nxt
  }

  // epilogue: reduce lsum over qd groups, normalize, pack 4 d-values -> 8B stores
#pragma unroll
  for (int rs = 0; rs < 2; rs++) {
    float s = lsum[rs];
    s += __shfl_xor(s, 16);
    s += __shfl_xor(s, 32);
    float rinv = 1.0f / s;
    int n = n0 + w * 32 + rs * 16 + l15;
    uint16_t* orow = ot + (size_t)b * 524288 + (size_t)n * 512 + h * 64;
#pragma unroll
    for (int dt = 0; dt < 4; dt++) {
      union { uint16_t u[4]; uint2 v; } pk;
#pragma unroll
      for (int r = 0; r < 4; r++) pk.u[r] = f2bf(oaccT[rs][dt][r] * rinv);
      *(uint2*)(orow + dt * 16 + qd * 4) = pk.v;
    }
  }
}

extern "C" void kernel_launch(void* const* d_in, const int* in_sizes, int n_in,
                              void* d_out, int out_size, void* d_ws, size_t ws_size,
                              hipStream_t stream) {
  (void)in_sizes; (void)n_in; (void)out_size; (void)ws_size;
  const float* xf   = (const float*)d_in[0];
  const float* gamf = (const float*)d_in[1];
  const float* betf = (const float*)d_in[2];
  const float* wqf  = (const float*)d_in[3];
  const float* wpf  = (const float*)d_in[4];
  const float* bprf = (const float*)d_in[5];
  float* out = (float*)d_out;

  uint16_t* base = (uint16_t*)d_ws;
  float* stats   = (float*)base;           // 512 floats (partial s1,s2 x 256)
  uint16_t* wqb  = base + 1024;
  uint16_t* wpb  = wqb + 786432;
  uint16_t* xn   = wpb + 262144;           // (B,N,C); reused as otw after gemm01
  uint16_t* qtw  = xn  + 4194304;          // (B,H,N,hd), Q pre-scaled by 1/8
  uint16_t* ktw  = qtw + 4194304;          // (B,H,N,hd)
  uint16_t* vtw  = ktw + 4194304;          // (B, h*64+d, N)
  uint16_t* otw  = xn;

  prep_k<<<768, 256, 0, stream>>>(wqf, wpf, wqb, wpb, xf, stats);
  gn_apply_k<<<dim3(16, 8, 8), 256, 0, stream>>>(xf, gamf, betf, stats, xn);
  gemm01_k<<<768, 256, 0, stream>>>(xn, wqb, qtw, ktw, vtw);
  attn_k<<<dim3(64, 8), 256, 0, stream>>>(qtw, ktw, vtw, otw);
  gemm2_k<<<256, 256, 0, stream>>>(wpb, otw, xf, bprf, out);
}